// Round 6
// baseline (3115.914 us; speedup 1.0000x reference)
//
#include <hip/hip_runtime.h>
#include <hip/hip_bf16.h>
#include <math.h>

// ---------------------------------------------------------------------------
// Hypergraph kNN, fp32-faithful to a numpy float32 reference:
//   eud[i,j] = sqrt( np.sum( (f[i]-f[j])**2 ) )   <-- DIRECT form (original
//   torch formulation), NOT the ||i||^2+||j||^2-2*dot trick of the jax code.
//   distances = adj/np.sum(adj,1) + eud/np.sum(eud,1);  top-9 per row.
// Row sums / k-sums use numpy's exact pairwise order (128-leaves, 8 accs).
// Phase 1 (selection only, noise-immune): fast trick-GEMM -> u16 eud + leaf
//   sums (diag forced 0) -> per-row top-64 candidates (err ~2e-9 << 1.5e-6).
// Phase 2: re-score 64 candidates with the DIRECT np-ordered fp32 form,
//   stable top-9 (ties -> lowest index), emit [src | dst | weights] as f32.
// ---------------------------------------------------------------------------

__device__ __forceinline__ float fbar(float x) {  // block FMA contraction
  asm volatile("" : "+v"(x));
  return x;
}

// ---- sq_norms: np.sum(f*f, axis=1) in exact numpy fp32 pairwise order -----
__global__ __launch_bounds__(128) void knn_sqn_np(const float* __restrict__ f,
                                                  float* __restrict__ sqn32,
                                                  int N, int D) {
  int row = blockIdx.x;             // D == 512: 4 leaves of 128
  int t = threadIdx.x;              // 128 threads
  __shared__ float a[512];
  __shared__ float R[4][8];
  const float* fr = f + (size_t)row * D;
  float4 v = ((const float4*)fr)[t];
  a[t * 4 + 0] = v.x * v.x;
  a[t * 4 + 1] = v.y * v.y;
  a[t * 4 + 2] = v.z * v.z;
  a[t * 4 + 3] = v.w * v.w;
  __syncthreads();
  if (t < 32) {
    int lf = t >> 3, m = t & 7;
    float s = a[lf * 128 + m];
    for (int g = 1; g < 16; ++g) s += a[lf * 128 + 8 * g + m];
    R[lf][m] = s;
  }
  __syncthreads();
  if (t == 0) {
    float L[4];
#pragma unroll
    for (int lf = 0; lf < 4; ++lf)
      L[lf] = ((R[lf][0] + R[lf][1]) + (R[lf][2] + R[lf][3])) +
              ((R[lf][4] + R[lf][5]) + (R[lf][6] + R[lf][7]));
    sqn32[row] = (L[0] + L[1]) + (L[2] + L[3]);
  }
}

// ---- Sa: np.sum(adj, axis=1) exact pairwise (N = 8192: 64 leaves) ---------
__global__ __launch_bounds__(256) void knn_sa_np(const float* __restrict__ A,
                                                 float* __restrict__ S, int N) {
  int row = blockIdx.x;
  int t = threadIdx.x;  // 256
  __shared__ float ch[2048];
  __shared__ float R[64][8];
  __shared__ float Lf[64];
  const float* ar = A + (size_t)row * N;
  for (int c = 0; c < 4; ++c) {  // 4 chunks of 2048 = 16 leaves each
    ((float4*)ch)[t]       = ((const float4*)(ar + c * 2048))[t];
    ((float4*)ch)[256 + t] = ((const float4*)(ar + c * 2048))[256 + t];
    __syncthreads();
    if (t < 128) {
      int lf = t >> 3, m = t & 7;
      float s = ch[lf * 128 + m];
      for (int g = 1; g < 16; ++g) s += ch[lf * 128 + 8 * g + m];
      R[c * 16 + lf][m] = s;
    }
    __syncthreads();
  }
  if (t < 64)
    Lf[t] = ((R[t][0] + R[t][1]) + (R[t][2] + R[t][3])) +
            ((R[t][4] + R[t][5]) + (R[t][6] + R[t][7]));
  __syncthreads();
  for (int w = 32; w >= 1; w >>= 1) {
    if (t < w) Lf[t] = Lf[2 * t] + Lf[2 * t + 1];
    __syncthreads();
  }
  if (t == 0) S[row] = Lf[0];
}

// ---- trick-GEMM tile -> u16 eud + fp32 leaf sums (phase-1 selection only) -
#define GBM 64
#define GBN 128
#define GKB 32
__global__ __launch_bounds__(256) void knn_gemm(const float* __restrict__ f,
                                                const float* __restrict__ sqn32,
                                                unsigned short* __restrict__ eud,
                                                float* __restrict__ leaf,
                                                int N, int D) {
  __shared__ float As[GBM][GKB + 1];
  __shared__ float Bs[GBN][GKB + 1];
  __shared__ float Et[GBM][GBN];
  __shared__ float R2[GBM][8];
  int bx = blockIdx.x;  // j tile == numpy leaf index
  int by = blockIdx.y;  // i tile
  int tid = threadIdx.x;
  int tx = tid & 15, ty = tid >> 4;
  int i0 = by * GBM, j0 = bx * GBN;
  float acc[4][8] = {};

  for (int k0 = 0; k0 < D; k0 += GKB) {
#pragma unroll
    for (int l = 0; l < 2; ++l) {
      int idx = tid + l * 256;
      int r = idx >> 3, kg = idx & 7;
      float4 v = *(const float4*)(f + (size_t)(i0 + r) * D + k0 + kg * 4);
      As[r][kg * 4 + 0] = v.x; As[r][kg * 4 + 1] = v.y;
      As[r][kg * 4 + 2] = v.z; As[r][kg * 4 + 3] = v.w;
    }
#pragma unroll
    for (int l = 0; l < 4; ++l) {
      int idx = tid + l * 256;
      int r = idx >> 3, kg = idx & 7;
      float4 v = *(const float4*)(f + (size_t)(j0 + r) * D + k0 + kg * 4);
      Bs[r][kg * 4 + 0] = v.x; Bs[r][kg * 4 + 1] = v.y;
      Bs[r][kg * 4 + 2] = v.z; Bs[r][kg * 4 + 3] = v.w;
    }
    __syncthreads();
#pragma unroll
    for (int k = 0; k < GKB; ++k) {
      float a[4], b[8];
#pragma unroll
      for (int r = 0; r < 4; ++r) a[r] = As[ty * 4 + r][k];
#pragma unroll
      for (int c = 0; c < 8; ++c) b[c] = Bs[tx * 8 + c][k];
#pragma unroll
      for (int r = 0; r < 4; ++r)
#pragma unroll
        for (int c = 0; c < 8; ++c)
          acc[r][c] = __builtin_fmaf(a[r], b[c], acc[r][c]);
    }
    __syncthreads();
  }

  // epilogue: e approx; diag forced 0 (direct form gives exactly 0 there)
#pragma unroll
  for (int r = 0; r < 4; ++r) {
    int i = i0 + ty * 4 + r;
    float si = sqn32[i];
    unsigned short pk[8];
#pragma unroll
    for (int c = 0; c < 8; ++c) {
      int j = j0 + tx * 8 + c;
      float t1 = si + sqn32[j];
      float t2 = fbar(2.0f * acc[r][c]);
      float sq = t1 - t2;
      float e = (sq > 0.0f && i != j) ? (float)sqrt((double)sq) : 0.0f;
      Et[ty * 4 + r][tx * 8 + c] = e;
      int q = (int)(e * 1024.0f + 0.5f);
      if (q > 65535) q = 65535;
      pk[c] = (unsigned short)q;
    }
    *(ushort4*)(eud + (size_t)i * N + j0 + tx * 8)     = *(ushort4*)&pk[0];
    *(ushort4*)(eud + (size_t)i * N + j0 + tx * 8 + 4) = *(ushort4*)&pk[4];
  }
  __syncthreads();

  // numpy leaf sum over this 128-wide tile: 8 residue chains then combine
#pragma unroll
  for (int u0 = 0; u0 < 2; ++u0) {
    int u = tid + u0 * 256;
    int row = u >> 3, m = u & 7;
    float s = Et[row][m];
    for (int g = 1; g < 16; ++g) s += Et[row][8 * g + m];
    R2[row][m] = s;
  }
  __syncthreads();
  if (tid < 64) {
    float v = ((R2[tid][0] + R2[tid][1]) + (R2[tid][2] + R2[tid][3])) +
              ((R2[tid][4] + R2[tid][5]) + (R2[tid][6] + R2[tid][7]));
    leaf[(size_t)(i0 + tid) * 64 + bx] = v;
  }
}

// ---- Se: balanced binary tree over the 64 leaf sums (numpy order) ---------
__global__ __launch_bounds__(64) void knn_se_tree(const float* __restrict__ leaf,
                                                  float* __restrict__ Se, int N) {
  int row = blockIdx.x;
  int t = threadIdx.x;  // 64
  __shared__ float Lf[64];
  Lf[t] = leaf[(size_t)row * 64 + t];
  __syncthreads();
  for (int w = 32; w >= 1; w >>= 1) {
    if (t < w) Lf[t] = Lf[2 * t] + Lf[2 * t + 1];
    __syncthreads();
  }
  if (t == 0) Se[row] = Lf[0];
}

// ---- per-row top-64 candidate selection (approx fp32 scores) --------------
#define SWP(a, b, ia, ib) { float _t = a; a = b; b = _t; int _q = ia; ia = ib; ib = _q; }
#define INS(s, jj)                                        \
  if ((s) > v7) {                                         \
    v7 = (s); x7 = (jj);                                  \
    if (v7 > v6) SWP(v6, v7, x6, x7)                      \
    if (v6 > v5) SWP(v5, v6, x5, x6)                      \
    if (v5 > v4) SWP(v4, v5, x4, x5)                      \
    if (v4 > v3) SWP(v3, v4, x3, x4)                      \
    if (v3 > v2) SWP(v2, v3, x2, x3)                      \
    if (v2 > v1) SWP(v1, v2, x1, x2)                      \
    if (v1 > v0) SWP(v0, v1, x0, x1)                      \
  }

__global__ __launch_bounds__(256) void knn_select(const float* __restrict__ adj,
                                                  const unsigned short* __restrict__ eud,
                                                  const float* __restrict__ Sa,
                                                  const float* __restrict__ Se,
                                                  int* __restrict__ cand,
                                                  int N) {
  int row = blockIdx.x;
  const float* ar = adj + (size_t)row * N;
  const unsigned short* er = eud + (size_t)row * N;
  float ra = 1.0f / Sa[row];
  float re = (float)(1.0 / ((double)Se[row] * 1024.0));
  int t = threadIdx.x;

  float v0 = -3.0e38f, v1 = -3.0e38f, v2 = -3.0e38f, v3 = -3.0e38f;
  float v4 = -3.0e38f, v5 = -3.0e38f, v6 = -3.0e38f, v7 = -3.0e38f;
  int x0 = 0, x1 = 0, x2 = 0, x3 = 0, x4 = 0, x5 = 0, x6 = 0, x7 = 0;

  for (int it = 0; it < N / 1024; ++it) {
    int j = it * 1024 + t * 4;
    float4 av = *(const float4*)(ar + j);
    ushort4 ev = *(const ushort4*)(er + j);
    float s0 = av.x * ra + (float)ev.x * re;
    float s1 = av.y * ra + (float)ev.y * re;
    float s2 = av.z * ra + (float)ev.z * re;
    float s3 = av.w * ra + (float)ev.w * re;
    INS(s0, j + 0)
    INS(s1, j + 1)
    INS(s2, j + 2)
    INS(s3, j + 3)
  }

  __shared__ float lv[2048];
  __shared__ int   lx[2048];
  lv[t +    0] = v0; lx[t +    0] = x0;
  lv[t +  256] = v1; lx[t +  256] = x1;
  lv[t +  512] = v2; lx[t +  512] = x2;
  lv[t +  768] = v3; lx[t +  768] = x3;
  lv[t + 1024] = v4; lx[t + 1024] = x4;
  lv[t + 1280] = v5; lx[t + 1280] = x5;
  lv[t + 1536] = v6; lx[t + 1536] = x6;
  lv[t + 1792] = v7; lx[t + 1792] = x7;
  __syncthreads();

  if (t < 64) {
    unsigned mask = 0;  // picked slots among this lane's 32
    for (int sel = 0; sel < 64; ++sel) {
      float bv = -3.3e38f; int bs = 0;
      for (int m = 0; m < 32; ++m) {
        if (mask & (1u << m)) continue;
        float vv = lv[t + 64 * m];
        if (vv > bv) { bv = vv; bs = m; }
      }
      float cv = bv; int cl = t; int cs = bs;
      for (int off = 32; off; off >>= 1) {
        float ov = __shfl_xor(cv, off);
        int ol = __shfl_xor(cl, off);
        int os = __shfl_xor(cs, off);
        if (ov > cv || (ov == cv && ol < cl)) { cv = ov; cl = ol; cs = os; }
      }
      if (t == 0) cand[(size_t)row * 64 + sel] = lx[cl + 64 * cs];
      if (t == cl) mask |= (1u << cs);
    }
  }
}

// ---- phase 2: DIRECT np-ordered fp32 re-score of 64 cands, top-9, emit ----
__global__ __launch_bounds__(256) void knn_refine(const float* __restrict__ f,
                                                  const float* __restrict__ adj,
                                                  const float* __restrict__ Sa,
                                                  const float* __restrict__ Se,
                                                  const int* __restrict__ cand,
                                                  float* __restrict__ out,
                                                  int N, int D, int KP1) {
  int wave = threadIdx.x >> 6, lane = threadIdx.x & 63;
  int row = blockIdx.x * 4 + wave;

  __shared__ float sval[4][64];
  __shared__ int   sidx[4][64];

  float sa = Sa[row], se = Se[row];
  const float* fi = f + (size_t)row * D;

  int j = cand[(size_t)row * 64 + lane];
  const float* fj = f + (size_t)j * D;

  // np.sum(((f[i]-f[j])**2), axis=-1) in numpy pairwise order:
  // 4 leaves of 128; each leaf: 8 accumulators stride-8; combine
  // ((r0+r1)+(r2+r3))+((r4+r5)+(r6+r7)); leaves: (L0+L1)+(L2+L3).
  // Each term: d = fl(a-b); t = fl(d*d); acc = fl(acc + t)  (no FMA).
  float L[4];
#pragma unroll
  for (int lf = 0; lf < 4; ++lf) {
    const float* ai = fi + lf * 128;
    const float* bi = fj + lf * 128;
    float r8[8];
    {
      float4 a0 = *(const float4*)(ai);
      float4 a1 = *(const float4*)(ai + 4);
      float4 b0 = *(const float4*)(bi);
      float4 b1 = *(const float4*)(bi + 4);
      float d0 = a0.x - b0.x, d1 = a0.y - b0.y, d2 = a0.z - b0.z, d3 = a0.w - b0.w;
      float d4 = a1.x - b1.x, d5 = a1.y - b1.y, d6 = a1.z - b1.z, d7 = a1.w - b1.w;
      r8[0] = fbar(d0 * d0); r8[1] = fbar(d1 * d1);
      r8[2] = fbar(d2 * d2); r8[3] = fbar(d3 * d3);
      r8[4] = fbar(d4 * d4); r8[5] = fbar(d5 * d5);
      r8[6] = fbar(d6 * d6); r8[7] = fbar(d7 * d7);
    }
#pragma unroll
    for (int g = 1; g < 16; ++g) {
      float4 a0 = *(const float4*)(ai + 8 * g);
      float4 a1 = *(const float4*)(ai + 8 * g + 4);
      float4 b0 = *(const float4*)(bi + 8 * g);
      float4 b1 = *(const float4*)(bi + 8 * g + 4);
      float d0 = a0.x - b0.x, d1 = a0.y - b0.y, d2 = a0.z - b0.z, d3 = a0.w - b0.w;
      float d4 = a1.x - b1.x, d5 = a1.y - b1.y, d6 = a1.z - b1.z, d7 = a1.w - b1.w;
      r8[0] = r8[0] + fbar(d0 * d0); r8[1] = r8[1] + fbar(d1 * d1);
      r8[2] = r8[2] + fbar(d2 * d2); r8[3] = r8[3] + fbar(d3 * d3);
      r8[4] = r8[4] + fbar(d4 * d4); r8[5] = r8[5] + fbar(d5 * d5);
      r8[6] = r8[6] + fbar(d6 * d6); r8[7] = r8[7] + fbar(d7 * d7);
    }
    L[lf] = ((r8[0] + r8[1]) + (r8[2] + r8[3])) +
            ((r8[4] + r8[5]) + (r8[6] + r8[7]));
  }
  float sq = (L[0] + L[1]) + (L[2] + L[3]);
  float e = sq > 0.0f ? (float)sqrt((double)sq) : 0.0f;

  float sc = adj[(size_t)row * N + j] / sa + e / se;
  sval[wave][lane] = sc;
  sidx[wave][lane] = j;
  __syncthreads();

  if (lane == 0) {
    size_t NK = (size_t)N * KP1;
    size_t ob = (size_t)row * KP1;
    for (int r = 0; r < KP1; ++r) {
      float bv = -1.0f; int bj = 1 << 30; int bc = 0;
      for (int c = 0; c < 64; ++c) {
        float v = sval[wave][c]; int jx = sidx[wave][c];
        if (v > bv || (v == bv && jx < bj)) { bv = v; bj = jx; bc = c; }
      }
      sval[wave][bc] = -2.0f;
      out[ob + r]          = (float)row;  // edge_index row 0 (src)
      out[NK + ob + r]     = (float)bj;   // edge_index row 1 (dst)
      out[2 * NK + ob + r] = bv;          // edge_weights (faithful fp32)
    }
  }
}

static inline size_t alignup(size_t x, size_t a) { return (x + a - 1) & ~(a - 1); }

extern "C" void kernel_launch(void* const* d_in, const int* in_sizes, int n_in,
                              void* d_out, int out_size, void* d_ws, size_t ws_size,
                              hipStream_t stream) {
  const float* f   = (const float*)d_in[0];
  const float* adj = (const float*)d_in[1];

  long long nn = in_sizes[1];
  int N = (int)llround(sqrt((double)nn));
  int D = in_sizes[0] / N;
  int KP1 = out_size / (3 * N);

  char* w = (char*)d_ws;
  size_t off = 0;
  float* sqn32 = (float*)(w + off); off = alignup(off + (size_t)N * 4, 256);
  float* Sa    = (float*)(w + off); off = alignup(off + (size_t)N * 4, 256);
  float* Se    = (float*)(w + off); off = alignup(off + (size_t)N * 4, 256);
  float* leaf  = (float*)(w + off); off = alignup(off + (size_t)N * 64 * 4, 256);
  int* cand    = (int*)(w + off);   off = alignup(off + (size_t)N * 64 * 4, 256);
  unsigned short* eud = (unsigned short*)(w + off); off += (size_t)N * N * 2;
  (void)ws_size;

  knn_sqn_np<<<N, 128, 0, stream>>>(f, sqn32, N, D);
  knn_sa_np<<<N, 256, 0, stream>>>(adj, Sa, N);
  knn_gemm<<<dim3(N / GBN, N / GBM), 256, 0, stream>>>(f, sqn32, eud, leaf, N, D);
  knn_se_tree<<<N, 64, 0, stream>>>(leaf, Se, N);
  knn_select<<<N, 256, 0, stream>>>(adj, eud, Sa, Se, cand, N);
  knn_refine<<<N / 4, 256, 0, stream>>>(f, adj, Sa, Se, cand, (float*)d_out,
                                        N, D, KP1);
}

// Round 7
// 1473.709 us; speedup vs baseline: 2.1143x; 2.1143x over previous
//
#include <hip/hip_runtime.h>
#include <hip/hip_bf16.h>
#include <math.h>

// ---------------------------------------------------------------------------
// Hypergraph kNN, fp32-faithful to a numpy float32 reference:
//   eud[i,j] = sqrt( np.sum( (f[i]-f[j])**2 ) )   (DIRECT form, verified r6)
//   distances = adj/np.sum(adj,1) + eud/np.sum(eud,1);  top-9 per row.
// Phase 1 (selection + Se only; noise budget ~1e-6 in score units):
//   split-bf16 MFMA GEMM (hi*hi + hi*lo + lo*hi, fp32 acc) -> u16 eud +
//   f32 per-tile row sums -> per-row top-64 candidates.
// Phase 2 (correctness-critical, unchanged from round 6): DIRECT np-ordered
//   fp32 re-score of 64 candidates, stable top-9, emit [src|dst|w] as f32.
// ---------------------------------------------------------------------------

typedef short bf16x8 __attribute__((ext_vector_type(8)));   // 8 bf16 (4 VGPR)
typedef float f32x4 __attribute__((ext_vector_type(4)));

__device__ __forceinline__ float fbar(float x) {  // block FMA contraction
  asm volatile("" : "+v"(x));
  return x;
}
__device__ __forceinline__ unsigned short f2bf(float x) {  // RNE
  union { float f; unsigned u; } v; v.f = x;
  unsigned r = (v.u + 0x7fffu + ((v.u >> 16) & 1u)) >> 16;
  return (unsigned short)r;
}
__device__ __forceinline__ float bf2f(unsigned short b) {
  union { unsigned u; float f; } v; v.u = ((unsigned)b) << 16; return v.f;
}

// ---- split f32 -> hi/lo bf16 planes ---------------------------------------
__global__ __launch_bounds__(256) void knn_cvt(const float* __restrict__ f,
                                               unsigned short* __restrict__ hi,
                                               unsigned short* __restrict__ lo,
                                               int n4) {
  int i = blockIdx.x * 256 + threadIdx.x;
  if (i >= n4) return;
  float4 v = ((const float4*)f)[i];
  ushort4 h, l;
  h.x = f2bf(v.x); l.x = f2bf(v.x - bf2f(h.x));
  h.y = f2bf(v.y); l.y = f2bf(v.y - bf2f(h.y));
  h.z = f2bf(v.z); l.z = f2bf(v.z - bf2f(h.z));
  h.w = f2bf(v.w); l.w = f2bf(v.w - bf2f(h.w));
  ((ushort4*)hi)[i] = h;
  ((ushort4*)lo)[i] = l;
}

// ---- sq_norms: np.sum(f*f, axis=1) in exact numpy fp32 pairwise order -----
__global__ __launch_bounds__(128) void knn_sqn_np(const float* __restrict__ f,
                                                  float* __restrict__ sqn32,
                                                  int N, int D) {
  int row = blockIdx.x;             // D == 512: 4 leaves of 128
  int t = threadIdx.x;              // 128 threads
  __shared__ float a[512];
  __shared__ float R[4][8];
  const float* fr = f + (size_t)row * D;
  float4 v = ((const float4*)fr)[t];
  a[t * 4 + 0] = v.x * v.x;
  a[t * 4 + 1] = v.y * v.y;
  a[t * 4 + 2] = v.z * v.z;
  a[t * 4 + 3] = v.w * v.w;
  __syncthreads();
  if (t < 32) {
    int lf = t >> 3, m = t & 7;
    float s = a[lf * 128 + m];
    for (int g = 1; g < 16; ++g) s += a[lf * 128 + 8 * g + m];
    R[lf][m] = s;
  }
  __syncthreads();
  if (t == 0) {
    float L[4];
#pragma unroll
    for (int lf = 0; lf < 4; ++lf)
      L[lf] = ((R[lf][0] + R[lf][1]) + (R[lf][2] + R[lf][3])) +
              ((R[lf][4] + R[lf][5]) + (R[lf][6] + R[lf][7]));
    sqn32[row] = (L[0] + L[1]) + (L[2] + L[3]);
  }
}

// ---- Sa: np.sum(adj, axis=1) exact pairwise (N = 8192: 64 leaves) ---------
__global__ __launch_bounds__(256) void knn_sa_np(const float* __restrict__ A,
                                                 float* __restrict__ S, int N) {
  int row = blockIdx.x;
  int t = threadIdx.x;  // 256
  __shared__ float ch[2048];
  __shared__ float R[64][8];
  __shared__ float Lf[64];
  const float* ar = A + (size_t)row * N;
  for (int c = 0; c < 4; ++c) {  // 4 chunks of 2048 = 16 leaves each
    ((float4*)ch)[t]       = ((const float4*)(ar + c * 2048))[t];
    ((float4*)ch)[256 + t] = ((const float4*)(ar + c * 2048))[256 + t];
    __syncthreads();
    if (t < 128) {
      int lf = t >> 3, m = t & 7;
      float s = ch[lf * 128 + m];
      for (int g = 1; g < 16; ++g) s += ch[lf * 128 + 8 * g + m];
      R[c * 16 + lf][m] = s;
    }
    __syncthreads();
  }
  if (t < 64)
    Lf[t] = ((R[t][0] + R[t][1]) + (R[t][2] + R[t][3])) +
            ((R[t][4] + R[t][5]) + (R[t][6] + R[t][7]));
  __syncthreads();
  for (int w = 32; w >= 1; w >>= 1) {
    if (t < w) Lf[t] = Lf[2 * t] + Lf[2 * t + 1];
    __syncthreads();
  }
  if (t == 0) S[row] = Lf[0];
}

// ---- split-bf16 MFMA GEMM: 128x128 tile, 4 waves, BK=32 -------------------
// acc = hi*hi + hi*lo + lo*hi  (fp32 MFMA accumulate; ~2^-22-grade dot)
#define TBM 128
#define TBN 128
#define TBK 32
__global__ __launch_bounds__(256) void knn_gemm_mfma(
    const unsigned short* __restrict__ fhi, const unsigned short* __restrict__ flo,
    const float* __restrict__ sqn32, unsigned short* __restrict__ eud,
    float* __restrict__ leaf, int N, int D) {
  __shared__ unsigned short Ah[128][40];  // pad 40: 2-way banks on b128 reads
  __shared__ unsigned short Al[128][40];
  __shared__ unsigned short Bh[128][40];
  __shared__ unsigned short Bl[128][40];
  __shared__ float psum[128][2];

  int tid = threadIdx.x;
  int bx = blockIdx.x;              // j tile == leaf index (128-wide)
  int by = blockIdx.y;              // i tile
  int i0 = by * TBM, j0 = bx * TBN;
  int wid = tid >> 6, l = tid & 63;
  int wr = wid >> 1, wc = wid & 1;  // wave -> 64x64 quadrant
  int lr = l & 15, lk = l >> 4;     // frag row/col, k-chunk

  f32x4 acc[4][4] = {};             // statically indexed only (unrolled)

  int sr = tid >> 1;                // staging row 0..127
  int sh = (tid & 1) << 4;          // k-half 0/16

  for (int k0 = 0; k0 < D; k0 += TBK) {
    size_t aoff = (size_t)(i0 + sr) * D + k0 + sh;
    size_t boff = (size_t)(j0 + sr) * D + k0 + sh;
    *(uint4*)&Ah[sr][sh]     = *(const uint4*)(fhi + aoff);
    *(uint4*)&Ah[sr][sh + 8] = *(const uint4*)(fhi + aoff + 8);
    *(uint4*)&Al[sr][sh]     = *(const uint4*)(flo + aoff);
    *(uint4*)&Al[sr][sh + 8] = *(const uint4*)(flo + aoff + 8);
    *(uint4*)&Bh[sr][sh]     = *(const uint4*)(fhi + boff);
    *(uint4*)&Bh[sr][sh + 8] = *(const uint4*)(fhi + boff + 8);
    *(uint4*)&Bl[sr][sh]     = *(const uint4*)(flo + boff);
    *(uint4*)&Bl[sr][sh + 8] = *(const uint4*)(flo + boff + 8);
    __syncthreads();

    bf16x8 ah[4], al_[4], bh[4], bl_[4];
#pragma unroll
    for (int fr = 0; fr < 4; ++fr) {
      ah[fr]  = *(const bf16x8*)&Ah[wr * 64 + fr * 16 + lr][lk * 8];
      al_[fr] = *(const bf16x8*)&Al[wr * 64 + fr * 16 + lr][lk * 8];
      bh[fr]  = *(const bf16x8*)&Bh[wc * 64 + fr * 16 + lr][lk * 8];
      bl_[fr] = *(const bf16x8*)&Bl[wc * 64 + fr * 16 + lr][lk * 8];
    }
#pragma unroll
    for (int fr = 0; fr < 4; ++fr)
#pragma unroll
      for (int fc = 0; fc < 4; ++fc) {
        acc[fr][fc] = __builtin_amdgcn_mfma_f32_16x16x32_bf16(
            ah[fr], bh[fc], acc[fr][fc], 0, 0, 0);
        acc[fr][fc] = __builtin_amdgcn_mfma_f32_16x16x32_bf16(
            ah[fr], bl_[fc], acc[fr][fc], 0, 0, 0);
        acc[fr][fc] = __builtin_amdgcn_mfma_f32_16x16x32_bf16(
            al_[fr], bh[fc], acc[fr][fc], 0, 0, 0);
      }
    __syncthreads();
  }

  // epilogue: e = sqrt(max(si+sj-2*dot,0)), diag 0; u16 store; f32 row sums
  float sj[4];
#pragma unroll
  for (int fc = 0; fc < 4; ++fc) sj[fc] = sqn32[j0 + wc * 64 + fc * 16 + lr];

#pragma unroll
  for (int fr = 0; fr < 4; ++fr) {
#pragma unroll
    for (int v = 0; v < 4; ++v) {
      int i = i0 + wr * 64 + fr * 16 + lk * 4 + v;
      float si = sqn32[i];
      float s = 0.0f;
#pragma unroll
      for (int fc = 0; fc < 4; ++fc) {
        int j = j0 + wc * 64 + fc * 16 + lr;
        float sq = si + sj[fc] - 2.0f * acc[fr][fc][v];
        float e = (sq > 0.0f && i != j) ? sqrtf(sq) : 0.0f;
        s += e;
        int q = (int)(e * 1024.0f + 0.5f);
        if (q > 65535) q = 65535;
        eud[(size_t)i * N + j] = (unsigned short)q;
      }
      // reduce across the 16 lanes (lr) sharing this row (fixed tree)
#pragma unroll
      for (int off = 1; off < 16; off <<= 1) s += __shfl_xor(s, off);
      if (lr == 0) psum[wr * 64 + fr * 16 + lk * 4 + v][wc] = s;
    }
  }
  __syncthreads();
  if (tid < 128)
    leaf[(size_t)(i0 + tid) * 64 + bx] = psum[tid][0] + psum[tid][1];
}

// ---- Se: balanced binary tree over the 64 leaf sums -----------------------
__global__ __launch_bounds__(64) void knn_se_tree(const float* __restrict__ leaf,
                                                  float* __restrict__ Se, int N) {
  int row = blockIdx.x;
  int t = threadIdx.x;  // 64
  __shared__ float Lf[64];
  Lf[t] = leaf[(size_t)row * 64 + t];
  __syncthreads();
  for (int w = 32; w >= 1; w >>= 1) {
    if (t < w) Lf[t] = Lf[2 * t] + Lf[2 * t + 1];
    __syncthreads();
  }
  if (t == 0) Se[row] = Lf[0];
}

// ---- per-row top-64 candidate selection (approx fp32 scores) --------------
#define SWP(a, b, ia, ib) { float _t = a; a = b; b = _t; int _q = ia; ia = ib; ib = _q; }
#define INS(s, jj)                                        \
  if ((s) > v7) {                                         \
    v7 = (s); x7 = (jj);                                  \
    if (v7 > v6) SWP(v6, v7, x6, x7)                      \
    if (v6 > v5) SWP(v5, v6, x5, x6)                      \
    if (v5 > v4) SWP(v4, v5, x4, x5)                      \
    if (v4 > v3) SWP(v3, v4, x3, x4)                      \
    if (v3 > v2) SWP(v2, v3, x2, x3)                      \
    if (v2 > v1) SWP(v1, v2, x1, x2)                      \
    if (v1 > v0) SWP(v0, v1, x0, x1)                      \
  }

__global__ __launch_bounds__(256) void knn_select(const float* __restrict__ adj,
                                                  const unsigned short* __restrict__ eud,
                                                  const float* __restrict__ Sa,
                                                  const float* __restrict__ Se,
                                                  int* __restrict__ cand,
                                                  int N) {
  int row = blockIdx.x;
  const float* ar = adj + (size_t)row * N;
  const unsigned short* er = eud + (size_t)row * N;
  float ra = 1.0f / Sa[row];
  float re = (float)(1.0 / ((double)Se[row] * 1024.0));
  int t = threadIdx.x;

  float v0 = -3.0e38f, v1 = -3.0e38f, v2 = -3.0e38f, v3 = -3.0e38f;
  float v4 = -3.0e38f, v5 = -3.0e38f, v6 = -3.0e38f, v7 = -3.0e38f;
  int x0 = 0, x1 = 0, x2 = 0, x3 = 0, x4 = 0, x5 = 0, x6 = 0, x7 = 0;

  for (int it = 0; it < N / 1024; ++it) {
    int j = it * 1024 + t * 4;
    float4 av = *(const float4*)(ar + j);
    ushort4 ev = *(const ushort4*)(er + j);
    float s0 = av.x * ra + (float)ev.x * re;
    float s1 = av.y * ra + (float)ev.y * re;
    float s2 = av.z * ra + (float)ev.z * re;
    float s3 = av.w * ra + (float)ev.w * re;
    INS(s0, j + 0)
    INS(s1, j + 1)
    INS(s2, j + 2)
    INS(s3, j + 3)
  }

  __shared__ float lv[2048];
  __shared__ int   lx[2048];
  lv[t +    0] = v0; lx[t +    0] = x0;
  lv[t +  256] = v1; lx[t +  256] = x1;
  lv[t +  512] = v2; lx[t +  512] = x2;
  lv[t +  768] = v3; lx[t +  768] = x3;
  lv[t + 1024] = v4; lx[t + 1024] = x4;
  lv[t + 1280] = v5; lx[t + 1280] = x5;
  lv[t + 1536] = v6; lx[t + 1536] = x6;
  lv[t + 1792] = v7; lx[t + 1792] = x7;
  __syncthreads();

  if (t < 64) {
    unsigned mask = 0;  // picked slots among this lane's 32
    for (int sel = 0; sel < 64; ++sel) {
      float bv = -3.3e38f; int bs = 0;
      for (int m = 0; m < 32; ++m) {
        if (mask & (1u << m)) continue;
        float vv = lv[t + 64 * m];
        if (vv > bv) { bv = vv; bs = m; }
      }
      float cv = bv; int cl = t; int cs = bs;
      for (int off = 32; off; off >>= 1) {
        float ov = __shfl_xor(cv, off);
        int ol = __shfl_xor(cl, off);
        int os = __shfl_xor(cs, off);
        if (ov > cv || (ov == cv && ol < cl)) { cv = ov; cl = ol; cs = os; }
      }
      if (t == 0) cand[(size_t)row * 64 + sel] = lx[cl + 64 * cs];
      if (t == cl) mask |= (1u << cs);
    }
  }
}

// ---- phase 2: DIRECT np-ordered fp32 re-score of 64 cands, top-9, emit ----
__global__ __launch_bounds__(256) void knn_refine(const float* __restrict__ f,
                                                  const float* __restrict__ adj,
                                                  const float* __restrict__ Sa,
                                                  const float* __restrict__ Se,
                                                  const int* __restrict__ cand,
                                                  float* __restrict__ out,
                                                  int N, int D, int KP1) {
  int wave = threadIdx.x >> 6, lane = threadIdx.x & 63;
  int row = blockIdx.x * 4 + wave;

  __shared__ float sval[4][64];
  __shared__ int   sidx[4][64];

  float sa = Sa[row], se = Se[row];
  const float* fi = f + (size_t)row * D;

  int j = cand[(size_t)row * 64 + lane];
  const float* fj = f + (size_t)j * D;

  // np.sum(((f[i]-f[j])**2), axis=-1) in numpy pairwise order:
  // 4 leaves of 128; each leaf: 8 accumulators stride-8; combine
  // ((r0+r1)+(r2+r3))+((r4+r5)+(r6+r7)); leaves: (L0+L1)+(L2+L3).
  float L[4];
#pragma unroll
  for (int lf = 0; lf < 4; ++lf) {
    const float* ai = fi + lf * 128;
    const float* bi = fj + lf * 128;
    float r8[8];
    {
      float4 a0 = *(const float4*)(ai);
      float4 a1 = *(const float4*)(ai + 4);
      float4 b0 = *(const float4*)(bi);
      float4 b1 = *(const float4*)(bi + 4);
      float d0 = a0.x - b0.x, d1 = a0.y - b0.y, d2 = a0.z - b0.z, d3 = a0.w - b0.w;
      float d4 = a1.x - b1.x, d5 = a1.y - b1.y, d6 = a1.z - b1.z, d7 = a1.w - b1.w;
      r8[0] = fbar(d0 * d0); r8[1] = fbar(d1 * d1);
      r8[2] = fbar(d2 * d2); r8[3] = fbar(d3 * d3);
      r8[4] = fbar(d4 * d4); r8[5] = fbar(d5 * d5);
      r8[6] = fbar(d6 * d6); r8[7] = fbar(d7 * d7);
    }
#pragma unroll
    for (int g = 1; g < 16; ++g) {
      float4 a0 = *(const float4*)(ai + 8 * g);
      float4 a1 = *(const float4*)(ai + 8 * g + 4);
      float4 b0 = *(const float4*)(bi + 8 * g);
      float4 b1 = *(const float4*)(bi + 8 * g + 4);
      float d0 = a0.x - b0.x, d1 = a0.y - b0.y, d2 = a0.z - b0.z, d3 = a0.w - b0.w;
      float d4 = a1.x - b1.x, d5 = a1.y - b1.y, d6 = a1.z - b1.z, d7 = a1.w - b1.w;
      r8[0] = r8[0] + fbar(d0 * d0); r8[1] = r8[1] + fbar(d1 * d1);
      r8[2] = r8[2] + fbar(d2 * d2); r8[3] = r8[3] + fbar(d3 * d3);
      r8[4] = r8[4] + fbar(d4 * d4); r8[5] = r8[5] + fbar(d5 * d5);
      r8[6] = r8[6] + fbar(d6 * d6); r8[7] = r8[7] + fbar(d7 * d7);
    }
    L[lf] = ((r8[0] + r8[1]) + (r8[2] + r8[3])) +
            ((r8[4] + r8[5]) + (r8[6] + r8[7]));
  }
  float sq = (L[0] + L[1]) + (L[2] + L[3]);
  float e = sq > 0.0f ? (float)sqrt((double)sq) : 0.0f;

  float sc = adj[(size_t)row * N + j] / sa + e / se;
  sval[wave][lane] = sc;
  sidx[wave][lane] = j;
  __syncthreads();

  if (lane == 0) {
    size_t NK = (size_t)N * KP1;
    size_t ob = (size_t)row * KP1;
    for (int r = 0; r < KP1; ++r) {
      float bv = -1.0f; int bj = 1 << 30; int bc = 0;
      for (int c = 0; c < 64; ++c) {
        float v = sval[wave][c]; int jx = sidx[wave][c];
        if (v > bv || (v == bv && jx < bj)) { bv = v; bj = jx; bc = c; }
      }
      sval[wave][bc] = -2.0f;
      out[ob + r]          = (float)row;  // edge_index row 0 (src)
      out[NK + ob + r]     = (float)bj;   // edge_index row 1 (dst)
      out[2 * NK + ob + r] = bv;          // edge_weights (faithful fp32)
    }
  }
}

static inline size_t alignup(size_t x, size_t a) { return (x + a - 1) & ~(a - 1); }

extern "C" void kernel_launch(void* const* d_in, const int* in_sizes, int n_in,
                              void* d_out, int out_size, void* d_ws, size_t ws_size,
                              hipStream_t stream) {
  const float* f   = (const float*)d_in[0];
  const float* adj = (const float*)d_in[1];

  long long nn = in_sizes[1];
  int N = (int)llround(sqrt((double)nn));
  int D = in_sizes[0] / N;
  int KP1 = out_size / (3 * N);

  char* w = (char*)d_ws;
  size_t off = 0;
  float* sqn32 = (float*)(w + off); off = alignup(off + (size_t)N * 4, 256);
  float* Sa    = (float*)(w + off); off = alignup(off + (size_t)N * 4, 256);
  float* Se    = (float*)(w + off); off = alignup(off + (size_t)N * 4, 256);
  float* leaf  = (float*)(w + off); off = alignup(off + (size_t)N * 64 * 4, 256);
  int* cand    = (int*)(w + off);   off = alignup(off + (size_t)N * 64 * 4, 256);
  unsigned short* fhi = (unsigned short*)(w + off); off = alignup(off + (size_t)N * D * 2, 256);
  unsigned short* flo = (unsigned short*)(w + off); off = alignup(off + (size_t)N * D * 2, 256);
  unsigned short* eud = (unsigned short*)(w + off); off += (size_t)N * N * 2;
  (void)ws_size;

  int n4 = N * D / 4;
  knn_cvt<<<(n4 + 255) / 256, 256, 0, stream>>>(f, fhi, flo, n4);
  knn_sqn_np<<<N, 128, 0, stream>>>(f, sqn32, N, D);
  knn_sa_np<<<N, 256, 0, stream>>>(adj, Sa, N);
  knn_gemm_mfma<<<dim3(N / TBN, N / TBM), 256, 0, stream>>>(fhi, flo, sqn32,
                                                            eud, leaf, N, D);
  knn_se_tree<<<N, 64, 0, stream>>>(leaf, Se, N);
  knn_select<<<N, 256, 0, stream>>>(adj, eud, Sa, Se, cand, N);
  knn_refine<<<N / 4, 256, 0, stream>>>(f, adj, Sa, Se, cand, (float*)d_out,
                                        N, D, KP1);
}

// Round 9
// 1028.686 us; speedup vs baseline: 3.0290x; 1.4326x over previous
//
#include <hip/hip_runtime.h>
#include <hip/hip_bf16.h>
#include <math.h>

// ---------------------------------------------------------------------------
// Hypergraph kNN, fp32-faithful to a numpy float32 reference:
//   eud[i,j] = sqrt( np.sum( (f[i]-f[j])**2 ) )   (DIRECT form, verified r6)
//   distances = adj/np.sum(adj,1) + eud/np.sum(eud,1);  top-9 per row.
// Phase 1: split-bf16 MFMA GEMM (hi*hi+hi*lo+lo*hi, e err ~1e-6) -> u16 eud
//   + NUMPY-ORDERED fp32 leaf sums (LDS e-tile; Se differential ~3e-10 —
//   r8's failure was Se-order/precision differential at ~4e-7, lambda~0.4).
//   Fused rowsel: exact-numpy Sa + Se tree + per-wave top-16 -> 64 cands.
// Phase 2 (unchanged, r6-verified): DIRECT np-ordered fp32 re-score of 64
//   candidates, stable top-9, emit [src|dst|w] as f32.
// ---------------------------------------------------------------------------

typedef short bf16x8 __attribute__((ext_vector_type(8)));   // 8 bf16 (4 VGPR)
typedef float f32x4 __attribute__((ext_vector_type(4)));

__device__ __forceinline__ float fbar(float x) {  // block FMA contraction
  asm volatile("" : "+v"(x));
  return x;
}
__device__ __forceinline__ unsigned short f2bf(float x) {  // RNE
  union { float f; unsigned u; } v; v.f = x;
  unsigned r = (v.u + 0x7fffu + ((v.u >> 16) & 1u)) >> 16;
  return (unsigned short)r;
}
__device__ __forceinline__ float bf2f(unsigned short b) {
  union { unsigned u; float f; } v; v.u = ((unsigned)b) << 16; return v.f;
}

// ---- split f32 -> hi/lo bf16 planes ---------------------------------------
__global__ __launch_bounds__(256) void knn_cvt(const float* __restrict__ f,
                                               unsigned short* __restrict__ hi,
                                               unsigned short* __restrict__ lo,
                                               int n4) {
  int i = blockIdx.x * 256 + threadIdx.x;
  if (i >= n4) return;
  float4 v = ((const float4*)f)[i];
  ushort4 h, l;
  h.x = f2bf(v.x); l.x = f2bf(v.x - bf2f(h.x));
  h.y = f2bf(v.y); l.y = f2bf(v.y - bf2f(h.y));
  h.z = f2bf(v.z); l.z = f2bf(v.z - bf2f(h.z));
  h.w = f2bf(v.w); l.w = f2bf(v.w - bf2f(h.w));
  ((ushort4*)hi)[i] = h;
  ((ushort4*)lo)[i] = l;
}

// ---- sq_norms: np.sum(f*f, axis=1) in exact numpy fp32 pairwise order -----
__global__ __launch_bounds__(128) void knn_sqn_np(const float* __restrict__ f,
                                                  float* __restrict__ sqn32,
                                                  int N, int D) {
  int row = blockIdx.x;             // D == 512: 4 leaves of 128
  int t = threadIdx.x;              // 128 threads
  __shared__ float a[512];
  __shared__ float R[4][8];
  const float* fr = f + (size_t)row * D;
  float4 v = ((const float4*)fr)[t];
  a[t * 4 + 0] = v.x * v.x;
  a[t * 4 + 1] = v.y * v.y;
  a[t * 4 + 2] = v.z * v.z;
  a[t * 4 + 3] = v.w * v.w;
  __syncthreads();
  if (t < 32) {
    int lf = t >> 3, m = t & 7;
    float s = a[lf * 128 + m];
    for (int g = 1; g < 16; ++g) s += a[lf * 128 + 8 * g + m];
    R[lf][m] = s;
  }
  __syncthreads();
  if (t == 0) {
    float L[4];
#pragma unroll
    for (int lf = 0; lf < 4; ++lf)
      L[lf] = ((R[lf][0] + R[lf][1]) + (R[lf][2] + R[lf][3])) +
              ((R[lf][4] + R[lf][5]) + (R[lf][6] + R[lf][7]));
    sqn32[row] = (L[0] + L[1]) + (L[2] + L[3]);
  }
}

// ---- split-bf16 MFMA GEMM: 128x128 tile, 4 waves, BK=32 -------------------
// epilogue computes numpy-ordered 128-wide leaf sums from an LDS e-tile
#define TBM 128
#define TBN 128
#define TBK 32
__global__ __launch_bounds__(256) void knn_gemm_mfma(
    const unsigned short* __restrict__ fhi, const unsigned short* __restrict__ flo,
    const float* __restrict__ sqn32, unsigned short* __restrict__ eud,
    float* __restrict__ leaf, int N, int D) {
  // aliased LDS: staging (4 x 10240B) during k-loop; Et[64][132]+R2 in epilogue
  __shared__ __align__(16) char smem[40960];
  unsigned short (*Ah)[40] = (unsigned short(*)[40])(smem);
  unsigned short (*Al)[40] = (unsigned short(*)[40])(smem + 10240);
  unsigned short (*Bh)[40] = (unsigned short(*)[40])(smem + 20480);
  unsigned short (*Bl)[40] = (unsigned short(*)[40])(smem + 30720);

  int tid = threadIdx.x;
  int bx = blockIdx.x;              // j tile == numpy leaf index (128-wide)
  int by = blockIdx.y;              // i tile
  int i0 = by * TBM, j0 = bx * TBN;
  int wid = tid >> 6, l = tid & 63;
  int wr = wid >> 1, wc = wid & 1;  // wave -> 64x64 quadrant
  int lr = l & 15, lk = l >> 4;     // frag row, k-chunk

  f32x4 acc[4][4] = {};             // statically indexed only (unrolled)

  int sr = tid >> 1;                // staging row 0..127
  int sh = (tid & 1) << 4;          // k-half 0/16

  for (int k0 = 0; k0 < D; k0 += TBK) {
    size_t aoff = (size_t)(i0 + sr) * D + k0 + sh;
    size_t boff = (size_t)(j0 + sr) * D + k0 + sh;
    *(uint4*)&Ah[sr][sh]     = *(const uint4*)(fhi + aoff);
    *(uint4*)&Ah[sr][sh + 8] = *(const uint4*)(fhi + aoff + 8);
    *(uint4*)&Al[sr][sh]     = *(const uint4*)(flo + aoff);
    *(uint4*)&Al[sr][sh + 8] = *(const uint4*)(flo + aoff + 8);
    *(uint4*)&Bh[sr][sh]     = *(const uint4*)(fhi + boff);
    *(uint4*)&Bh[sr][sh + 8] = *(const uint4*)(fhi + boff + 8);
    *(uint4*)&Bl[sr][sh]     = *(const uint4*)(flo + boff);
    *(uint4*)&Bl[sr][sh + 8] = *(const uint4*)(flo + boff + 8);
    __syncthreads();

    bf16x8 ah[4], al_[4], bh[4], bl_[4];
#pragma unroll
    for (int fr = 0; fr < 4; ++fr) {
      ah[fr]  = *(const bf16x8*)&Ah[wr * 64 + fr * 16 + lr][lk * 8];
      al_[fr] = *(const bf16x8*)&Al[wr * 64 + fr * 16 + lr][lk * 8];
      bh[fr]  = *(const bf16x8*)&Bh[wc * 64 + fr * 16 + lr][lk * 8];
      bl_[fr] = *(const bf16x8*)&Bl[wc * 64 + fr * 16 + lr][lk * 8];
    }
#pragma unroll
    for (int fr = 0; fr < 4; ++fr)
#pragma unroll
      for (int fc = 0; fc < 4; ++fc) {
        acc[fr][fc] = __builtin_amdgcn_mfma_f32_16x16x32_bf16(
            ah[fr], bh[fc], acc[fr][fc], 0, 0, 0);
        acc[fr][fc] = __builtin_amdgcn_mfma_f32_16x16x32_bf16(
            ah[fr], bl_[fc], acc[fr][fc], 0, 0, 0);
        acc[fr][fc] = __builtin_amdgcn_mfma_f32_16x16x32_bf16(
            al_[fr], bh[fc], acc[fr][fc], 0, 0, 0);
      }
    __syncthreads();
  }

  // ---- epilogue: e values -> eud (u16) + LDS Et; numpy-ordered leaf sums --
  float (*Et)[132] = (float(*)[132])(smem);          // 64 rows x 132 (padded)
  float (*R2)[8]   = (float(*)[8])(smem + 33792);

  float sj[4];
#pragma unroll
  for (int fc = 0; fc < 4; ++fc) sj[fc] = sqn32[j0 + wc * 64 + fc * 16 + lr];

#pragma unroll
  for (int pass = 0; pass < 2; ++pass) {
    if (wr == pass) {
#pragma unroll
      for (int fr = 0; fr < 4; ++fr) {
#pragma unroll
        for (int v = 0; v < 4; ++v) {
          int irow = fr * 16 + lk * 4 + v;          // 0..63 within pass half
          int i = i0 + pass * 64 + irow;
          float si = sqn32[i];
#pragma unroll
          for (int fc = 0; fc < 4; ++fc) {
            int jcol = wc * 64 + fc * 16 + lr;
            int j = j0 + jcol;
            float sq = si + sj[fc] - 2.0f * acc[fr][fc][v];
            float e = (sq > 0.0f && i != j) ? sqrtf(sq) : 0.0f;
            Et[irow][jcol] = e;
            int q = (int)(e * 1024.0f + 0.5f);
            if (q > 65535) q = 65535;
            eud[(size_t)i * N + j] = (unsigned short)q;
          }
        }
      }
    }
    __syncthreads();
    // numpy leaf chains: 64 rows x 8 accumulators, stride-8 ascending
#pragma unroll
    for (int u0 = 0; u0 < 2; ++u0) {
      int u = tid + u0 * 256;                       // 0..511
      int row = u >> 3, m = u & 7;
      float s = Et[row][m];
#pragma unroll
      for (int g = 1; g < 16; ++g) s += Et[row][8 * g + m];
      R2[row][m] = s;
    }
    __syncthreads();
    if (tid < 64) {
      float v = ((R2[tid][0] + R2[tid][1]) + (R2[tid][2] + R2[tid][3])) +
                ((R2[tid][4] + R2[tid][5]) + (R2[tid][6] + R2[tid][7]));
      leaf[(size_t)(i0 + pass * 64 + tid) * 64 + bx] = v;
    }
    __syncthreads();
  }
}

// ---- fused: exact-numpy Sa + Se tree + per-wave top-16 selection ----------
#define SWP(a, b, ia, ib) { float _t = a; a = b; b = _t; int _q = ia; ia = ib; ib = _q; }
#define INS(s, jj)                                        \
  if ((s) > v7) {                                         \
    v7 = (s); x7 = (jj);                                  \
    if (v7 > v6) SWP(v6, v7, x6, x7)                      \
    if (v6 > v5) SWP(v5, v6, x5, x6)                      \
    if (v5 > v4) SWP(v4, v5, x4, x5)                      \
    if (v4 > v3) SWP(v3, v4, x3, x4)                      \
    if (v3 > v2) SWP(v2, v3, x2, x3)                      \
    if (v2 > v1) SWP(v1, v2, x1, x2)                      \
    if (v1 > v0) SWP(v0, v1, x0, x1)                      \
  }

__global__ __launch_bounds__(256) void knn_rowsel(
    const float* __restrict__ adj, const unsigned short* __restrict__ eud,
    const float* __restrict__ leaf, int* __restrict__ cand,
    float* __restrict__ SaOut, float* __restrict__ SeOut, int N) {
  __shared__ float arow[8192];
  __shared__ float R[64][8];
  __shared__ float Lf[64];
  __shared__ float bc[2];
  int row = blockIdx.x;
  int t = threadIdx.x;
  const float* ar = adj + (size_t)row * N;

  // stage adjacency row (32 KB) once
#pragma unroll
  for (int c = 0; c < 8; ++c)
    ((float4*)arow)[c * 256 + t] = ((const float4*)ar)[c * 256 + t];
  __syncthreads();

  // Sa: numpy pairwise order — 64 leaves of 128, 8 stride-8 accumulators
  for (int u = t; u < 512; u += 256) {
    int lf = u >> 3, m = u & 7;
    float s = arow[lf * 128 + m];
    for (int g = 1; g < 16; ++g) s += arow[lf * 128 + 8 * g + m];
    R[lf][m] = s;
  }
  __syncthreads();
  if (t < 64)
    Lf[t] = ((R[t][0] + R[t][1]) + (R[t][2] + R[t][3])) +
            ((R[t][4] + R[t][5]) + (R[t][6] + R[t][7]));
  __syncthreads();
  for (int w = 32; w >= 1; w >>= 1) {
    if (t < w) Lf[t] = Lf[2 * t] + Lf[2 * t + 1];
    __syncthreads();
  }
  if (t == 0) { float Sa = Lf[0]; SaOut[row] = Sa; bc[0] = 1.0f / Sa; }
  __syncthreads();

  // Se: balanced tree over the 64 numpy-ordered gemm leaf sums
  if (t < 64) Lf[t] = leaf[(size_t)row * 64 + t];
  __syncthreads();
  for (int w = 32; w >= 1; w >>= 1) {
    if (t < w) Lf[t] = Lf[2 * t] + Lf[2 * t + 1];
    __syncthreads();
  }
  if (t == 0) {
    float Se = Lf[0]; SeOut[row] = Se;
    bc[1] = (float)(1.0 / ((double)Se * 1024.0));
  }
  __syncthreads();
  float ra = bc[0], re = bc[1];

  // stream: per-thread top-8 of approx scores (adj from LDS, eud from HBM)
  const unsigned short* er = eud + (size_t)row * N;
  float v0 = -3.0e38f, v1 = -3.0e38f, v2 = -3.0e38f, v3 = -3.0e38f;
  float v4 = -3.0e38f, v5 = -3.0e38f, v6 = -3.0e38f, v7 = -3.0e38f;
  int x0 = 0, x1 = 0, x2 = 0, x3 = 0, x4 = 0, x5 = 0, x6 = 0, x7 = 0;
#pragma unroll
  for (int it = 0; it < 8; ++it) {
    int j = it * 1024 + t * 4;
    float4 av = *(const float4*)(arow + j);
    ushort4 ev = *(const ushort4*)(er + j);
    float s0 = av.x * ra + (float)ev.x * re;
    float s1 = av.y * ra + (float)ev.y * re;
    float s2 = av.z * ra + (float)ev.z * re;
    float s3 = av.w * ra + (float)ev.w * re;
    INS(s0, j + 0)
    INS(s1, j + 1)
    INS(s2, j + 2)
    INS(s3, j + 3)
  }

  // per-wave top-16 (wave owns a disjoint 2048-element subset; any global
  // approx-rank<=16 item is certainly included). 16 extractions, shfl-reduce.
  int lane = t & 63, wv = t >> 6;
  int* cw = cand + (size_t)row * 64 + wv * 16;
#pragma unroll
  for (int sel = 0; sel < 16; ++sel) {
    float cv = v0; int cj = x0;
    for (int off = 32; off; off >>= 1) {
      float ov = __shfl_xor(cv, off);
      int oj = __shfl_xor(cj, off);
      if (ov > cv || (ov == cv && oj < cj)) { cv = ov; cj = oj; }
    }
    if (lane == 0) cw[sel] = cj;
    if (v0 == cv && x0 == cj) {   // unique winner (j unique per thread)
      v0 = v1; x0 = x1; v1 = v2; x1 = x2; v2 = v3; x2 = x3; v3 = v4; x3 = x4;
      v4 = v5; x4 = x5; v5 = v6; x5 = x6; v6 = v7; x6 = x7;
      v7 = -3.0e38f; x7 = 0x7fffffff;
    }
  }
}

// ---- phase 2: DIRECT np-ordered fp32 re-score of 64 cands, top-9, emit ----
__global__ __launch_bounds__(256) void knn_refine(const float* __restrict__ f,
                                                  const float* __restrict__ adj,
                                                  const float* __restrict__ Sa,
                                                  const float* __restrict__ Se,
                                                  const int* __restrict__ cand,
                                                  float* __restrict__ out,
                                                  int N, int D, int KP1) {
  int wave = threadIdx.x >> 6, lane = threadIdx.x & 63;
  int row = blockIdx.x * 4 + wave;

  __shared__ float sval[4][64];
  __shared__ int   sidx[4][64];

  float sa = Sa[row], se = Se[row];
  const float* fi = f + (size_t)row * D;

  int j = cand[(size_t)row * 64 + lane];
  const float* fj = f + (size_t)j * D;

  // np.sum((f[i]-f[j])**2) in numpy pairwise order: 4 leaves of 128,
  // 8 stride-8 accumulators, ((r0+r1)+(r2+r3))+((r4+r5)+(r6+r7)), (L0+L1)+(L2+L3)
  float L[4];
#pragma unroll
  for (int lf = 0; lf < 4; ++lf) {
    const float* ai = fi + lf * 128;
    const float* bi = fj + lf * 128;
    float r8[8];
    {
      float4 a0 = *(const float4*)(ai);
      float4 a1 = *(const float4*)(ai + 4);
      float4 b0 = *(const float4*)(bi);
      float4 b1 = *(const float4*)(bi + 4);
      float d0 = a0.x - b0.x, d1 = a0.y - b0.y, d2 = a0.z - b0.z, d3 = a0.w - b0.w;
      float d4 = a1.x - b1.x, d5 = a1.y - b1.y, d6 = a1.z - b1.z, d7 = a1.w - b1.w;
      r8[0] = fbar(d0 * d0); r8[1] = fbar(d1 * d1);
      r8[2] = fbar(d2 * d2); r8[3] = fbar(d3 * d3);
      r8[4] = fbar(d4 * d4); r8[5] = fbar(d5 * d5);
      r8[6] = fbar(d6 * d6); r8[7] = fbar(d7 * d7);
    }
#pragma unroll
    for (int g = 1; g < 16; ++g) {
      float4 a0 = *(const float4*)(ai + 8 * g);
      float4 a1 = *(const float4*)(ai + 8 * g + 4);
      float4 b0 = *(const float4*)(bi + 8 * g);
      float4 b1 = *(const float4*)(bi + 8 * g + 4);
      float d0 = a0.x - b0.x, d1 = a0.y - b0.y, d2 = a0.z - b0.z, d3 = a0.w - b0.w;
      float d4 = a1.x - b1.x, d5 = a1.y - b1.y, d6 = a1.z - b1.z, d7 = a1.w - b1.w;
      r8[0] = r8[0] + fbar(d0 * d0); r8[1] = r8[1] + fbar(d1 * d1);
      r8[2] = r8[2] + fbar(d2 * d2); r8[3] = r8[3] + fbar(d3 * d3);
      r8[4] = r8[4] + fbar(d4 * d4); r8[5] = r8[5] + fbar(d5 * d5);
      r8[6] = r8[6] + fbar(d6 * d6); r8[7] = r8[7] + fbar(d7 * d7);
    }
    L[lf] = ((r8[0] + r8[1]) + (r8[2] + r8[3])) +
            ((r8[4] + r8[5]) + (r8[6] + r8[7]));
  }
  float sq = (L[0] + L[1]) + (L[2] + L[3]);
  float e = sq > 0.0f ? (float)sqrt((double)sq) : 0.0f;

  float sc = adj[(size_t)row * N + j] / sa + e / se;
  sval[wave][lane] = sc;
  sidx[wave][lane] = j;
  __syncthreads();

  if (lane == 0) {
    size_t NK = (size_t)N * KP1;
    size_t ob = (size_t)row * KP1;
    for (int r = 0; r < KP1; ++r) {
      float bv = -1.0f; int bj = 1 << 30; int bc = 0;
      for (int c = 0; c < 64; ++c) {
        float v = sval[wave][c]; int jx = sidx[wave][c];
        if (v > bv || (v == bv && jx < bj)) { bv = v; bj = jx; bc = c; }
      }
      sval[wave][bc] = -2.0f;
      out[ob + r]          = (float)row;  // edge_index row 0 (src)
      out[NK + ob + r]     = (float)bj;   // edge_index row 1 (dst)
      out[2 * NK + ob + r] = bv;          // edge_weights (faithful fp32)
    }
  }
}

static inline size_t alignup(size_t x, size_t a) { return (x + a - 1) & ~(a - 1); }

extern "C" void kernel_launch(void* const* d_in, const int* in_sizes, int n_in,
                              void* d_out, int out_size, void* d_ws, size_t ws_size,
                              hipStream_t stream) {
  const float* f   = (const float*)d_in[0];
  const float* adj = (const float*)d_in[1];

  long long nn = in_sizes[1];
  int N = (int)llround(sqrt((double)nn));
  int D = in_sizes[0] / N;
  int KP1 = out_size / (3 * N);

  char* w = (char*)d_ws;
  size_t off = 0;
  float* sqn32 = (float*)(w + off); off = alignup(off + (size_t)N * 4, 256);
  float* Sa    = (float*)(w + off); off = alignup(off + (size_t)N * 4, 256);
  float* Se    = (float*)(w + off); off = alignup(off + (size_t)N * 4, 256);
  float* leaf  = (float*)(w + off); off = alignup(off + (size_t)N * 64 * 4, 256);
  int* cand    = (int*)(w + off);   off = alignup(off + (size_t)N * 64 * 4, 256);
  unsigned short* fhi = (unsigned short*)(w + off); off = alignup(off + (size_t)N * D * 2, 256);
  unsigned short* flo = (unsigned short*)(w + off); off = alignup(off + (size_t)N * D * 2, 256);
  unsigned short* eud = (unsigned short*)(w + off); off += (size_t)N * N * 2;
  (void)ws_size;

  int n4 = N * D / 4;
  knn_cvt<<<(n4 + 255) / 256, 256, 0, stream>>>(f, fhi, flo, n4);
  knn_sqn_np<<<N, 128, 0, stream>>>(f, sqn32, N, D);
  knn_gemm_mfma<<<dim3(N / TBN, N / TBM), 256, 0, stream>>>(fhi, flo, sqn32,
                                                            eud, leaf, N, D);
  knn_rowsel<<<N, 256, 0, stream>>>(adj, eud, leaf, cand, Sa, Se, N);
  knn_refine<<<N / 4, 256, 0, stream>>>(f, adj, Sa, Se, cand, (float*)d_out,
                                        N, D, KP1);
}